// Round 13
// baseline (401.201 us; speedup 1.0000x reference)
//
#include <hip/hip_runtime.h>
#include <stdint.h>
#include <math.h>

#define N0 8192
#define HH 128
#define KN 5
#define SMALLD 31   // columns with (non-self in-deg) <= SMALLD use exact sequential gather
#define EL 16       // rank kernel: elements per block
#define CHK 16      // rank kernel: chunk-threads per element

__device__ inline void atomAddD(double* a, double v){
  __hip_atomic_fetch_add(a, v, __ATOMIC_RELAXED, __HIP_MEMORY_SCOPE_AGENT);
}

// ---- fused graph-structure kernel (single block, 1024 threads) ----
__global__ __launch_bounds__(1024) void graph_kernel(int* nbr, int n, int init,
    int* degi, float* dinvf, int* cnt, int* slots, double* T, double* TsPart){
  extern __shared__ int lds[];
  int* hist = lds;        // n ints
  int* cntL = lds + n;    // n ints
  const int t = threadIdx.x;
  const int lane = t & 63;
  if (init){
    for (int i=t;i<n;i+=1024){
      nbr[i*KN+0] = -1;                       // self (dedup vs implicit self-loop)
      int q=1, j=0;
      while (q<KN){ if (j!=i) nbr[i*KN+(q++)]=j; j++; }
    }
  }
  for (int i=t;i<n;i+=1024){ hist[i]=0; cntL[i]=0; }
  if (t<HH) T[t]=0.0;
  if (t<256) TsPart[t]=0.0;
  __syncthreads();
  // degree count; leader aggregation: hub targets are wave-uniform -> 1 atomic/wave
  for (int r=t;r<n;r+=1024){
    #pragma unroll
    for (int e=0;e<KN;e++){
      int c = nbr[r*KN+e];
      if (c>=0){
        int v = __builtin_amdgcn_readfirstlane(c);
        unsigned long long eq = __ballot(c==v);
        if (c==v){
          if ((eq & ((1ULL<<lane)-1ULL))==0ULL) atomicAdd(&hist[v], (int)__popcll(eq));
        } else {
          atomicAdd(&hist[c], 1);
        }
      }
    }
  }
  __syncthreads();
  for (int c2=t;c2<n;c2+=1024){
    degi[c2]=hist[c2];
    dinvf[c2]=1.0f/sqrtf((float)(hist[c2]+1));  // f32 CR sqrt+div, matches np
  }
  __syncthreads();
  for (int r=t;r<n;r+=1024){
    #pragma unroll
    for (int e=0;e<KN;e++){
      int c = nbr[r*KN+e];
      if (c>=0 && hist[c]<=SMALLD){
        int p = atomicAdd(&cntL[c],1);
        if (p<32) slots[c*32+p]=r;
      }
    }
  }
  __syncthreads();
  for (int c2=t;c2<n;c2+=1024){
    if (hist[c2]<=SMALLD){
      int m = cntL[c2];
      slots[c2*32+m]=c2; m++;
      for (int a=1;a<m;a++){
        int v2=slots[c2*32+a]; int b=a-1;
        while (b>=0 && slots[c2*32+b]>v2){ slots[c2*32+b+1]=slots[c2*32+b]; b--; }
        slots[c2*32+b+1]=v2;
      }
      cnt[c2]=m;
    }
  }
}

// G[c][j] = sequential f32 FMA dot, k = 0..127 ascending (bit-exact per output).
// r13: 4 rows/block, 4 cols/thread via float4 W loads — wave reads one full
// 512B W row (broadcast across half-waves); ~2 VALU/output vs 6 in r12.
__global__ __launch_bounds__(128) void gemm32_kernel(const float* __restrict__ X,
    const float* __restrict__ W, float* __restrict__ G, int n){
  int lg = threadIdx.x & 31;           // col group: j0 = 4*lg
  int rr = threadIdx.x >> 5;           // row within block (0..3)
  int c = blockIdx.x*4 + rr;
  int j0 = lg*4;
  const float* xr = X + (size_t)c*HH;
  float a0=0.0f,a1=0.0f,a2=0.0f,a3=0.0f;
  for (int k=0;k<HH;k++){
    float xv = xr[k];
    float4 wv = *(const float4*)(W + k*HH + j0);
    a0 = fmaf(xv, wv.x, a0);
    a1 = fmaf(xv, wv.y, a1);
    a2 = fmaf(xv, wv.z, a2);
    a3 = fmaf(xv, wv.w, a3);
  }
  *(float4*)(G + (size_t)c*HH + j0) = make_float4(a0,a1,a2,a3);
}

// parallel all-rows feature sums (hub columns only consume T)
__global__ __launch_bounds__(128) void tpar_kernel(const float* __restrict__ G,
    const float* __restrict__ dinvf, double* T, int n){
  double acc = 0.0;
  for (int r = blockIdx.x; r < n; r += gridDim.x)
    acc += (double)dinvf[r]*(double)G[(size_t)r*HH+threadIdx.x];
  atomAddD(&T[threadIdx.x], acc);
}

// fused: feature aggregation + relu + score projection + Ts partial
__global__ __launch_bounds__(128) void aggproj_kernel(const float* __restrict__ G,
    const float* __restrict__ dinvf, const int* __restrict__ degi,
    const int* __restrict__ cnt, const int* __restrict__ slots,
    const double* __restrict__ T, const float* __restrict__ Wp,
    float* __restrict__ hout, float* __restrict__ y, double* TsPart, int n){
  __shared__ float hrow[HH];
  int c = blockIdx.x, j = threadIdx.x;
  float v;
  if (degi[c] <= SMALLD){
    float acc = 0.0f, dc = dinvf[c];
    int m = cnt[c];
    for (int a=0;a<m;a++){
      int r = slots[c*32+a];
      acc = fmaf(dinvf[r]*dc, G[(size_t)r*HH+j], acc);
    }
    v = acc;
  } else {
    v = (float)((double)dinvf[c]*T[j]);
  }
  v = v<0.0f ? 0.0f : v;                    // relu
  hout[(size_t)c*HH+j] = v;
  hrow[j] = v;
  __syncthreads();
  if (j==0){
    float acc = 0.0f;
    for (int k=0;k<HH;k++) acc = fmaf(hrow[k], Wp[k], acc);  // np's sequential dot
    y[c] = acc;
    atomAddD(&TsPart[c & 255], (double)dinvf[c]*(double)acc);
  }
}

// score aggregation + key build; Ts recovered from partials in fixed order
__global__ __launch_bounds__(256) void sagg32_kernel(const float* __restrict__ y,
    const float* __restrict__ dinvf, const int* __restrict__ degi,
    const int* __restrict__ cnt, const int* __restrict__ slots,
    const double* __restrict__ TsPart, float* score, unsigned* key, int n){
  __shared__ double tp[256];
  tp[threadIdx.x] = TsPart[threadIdx.x];
  __syncthreads();
  for (int o=128;o>0;o>>=1){ if (threadIdx.x<o) tp[threadIdx.x]+=tp[threadIdx.x+o]; __syncthreads(); }
  double Ts = tp[0];                        // identical in every block (fixed order)
  int c = blockIdx.x*256+threadIdx.x; if (c>=n) return;
  float sc;
  if (degi[c] <= SMALLD){
    float acc = 0.0f, dc = dinvf[c];
    int m = cnt[c];
    for (int a=0;a<m;a++){ int r = slots[c*32+a]; acc = fmaf(dinvf[r]*dc, y[r], acc); }
    sc = acc;
  } else {
    sc = (float)((double)dinvf[c]*Ts);
  }
  score[c] = sc;
  unsigned s = __float_as_uint(sc);
  unsigned u = (s>>31) ? ~s : (s | 0x80000000u);   // order-preserving map
  key[c] = ~u;                                      // ascending key == descending score
}

// rank-by-counting stable top-k (bit-identical to stable desc sort + asc ties)
// r13: uint4 key loads + split-range compare: (kj<ke)||(kj==ke&&j<i) ==
// (kj<=ke) for j<i, (kj<ke) for j>=i — exact identity, count order-free.
__global__ __launch_bounds__(256) void rank_kernel(
    const unsigned* __restrict__ key, const float* __restrict__ score, int n,
    int* out_idx, float* gate, int* pos,
    const int* __restrict__ perm_prev, int* perm_next){
  __shared__ unsigned psum[EL][CHK+1];
  const int t = threadIdx.x;
  const int e = t & (EL-1), c = t >> 4;
  const int i = blockIdx.x*EL + e;
  const unsigned ke = key[i];
  const int L = n / CHK;                 // multiple of 4 (n >= 2048)
  const int j0 = c*L, j1 = j0+L;
  unsigned cnt = 0;
  for (int j=j0; j<j1; j+=4){
    if (j+4 <= i){
      uint4 kv = *(const uint4*)(key+j);
      cnt += (kv.x<=ke) + (kv.y<=ke) + (kv.z<=ke) + (kv.w<=ke);
    } else if (j >= i){
      uint4 kv = *(const uint4*)(key+j);
      cnt += (kv.x<ke) + (kv.y<ke) + (kv.z<ke) + (kv.w<ke);
    } else {                             // the single chunk containing i
      for (int q=j;q<j+4;q++){
        unsigned kj = key[q];
        cnt += (kj<ke || (kj==ke && q<i)) ? 1u : 0u;
      }
    }
  }
  psum[e][c] = cnt;
  __syncthreads();
  if (c == 0){
    unsigned r = 0;
    #pragma unroll
    for (int q=0;q<CHK;q++) r += psum[e][q];
    int m = n>>1;
    if ((int)r < m){
      out_idx[r] = i;
      gate[r] = (float)tanh((double)score[i]);   // correctly-rounded f32 tanh
      pos[i] = (int)r;
      perm_next[r] = perm_prev ? perm_prev[i] : i;
    } else {
      pos[i] = -1;
    }
  }
}

// fused pool (gate multiply) + neighbor remap
__global__ __launch_bounds__(128) void poolmap_kernel(const float* __restrict__ h,
    const int* __restrict__ idx, const float* __restrict__ gate,
    const int* __restrict__ nbr_prev, const int* __restrict__ pos,
    float* hp, int* nbr_next, int m){
  int i = blockIdx.x, j = threadIdx.x;
  int g = idx[i];
  hp[(size_t)i*HH+j] = h[(size_t)g*HH+j]*gate[i];
  if (j < KN){
    int o = nbr_prev[g*KN+j];
    nbr_next[i*KN+j] = (o>=0) ? pos[o] : -1;
  }
}

__global__ __launch_bounds__(256) void readout_kernel(const float* __restrict__ hp,
    double* rout, int m){
  int c = blockIdx.x;
  double mx = -INFINITY, sm = 0.0;
  for (int i=threadIdx.x;i<m;i+=256){ double v = hp[(size_t)i*HH+c]; mx = fmax(mx,v); sm += v; }
  for (int o=32;o>0;o>>=1){ mx = fmax(mx, __shfl_down(mx,o,64)); sm += __shfl_down(sm,o,64); }
  __shared__ double smx[4], ssm[4];
  int lane = threadIdx.x&63, w = threadIdx.x>>6;
  if (lane==0){ smx[w]=mx; ssm[w]=sm; }
  __syncthreads();
  if (threadIdx.x==0){
    mx = fmax(fmax(smx[0],smx[1]),fmax(smx[2],smx[3]));
    sm = ssm[0]+ssm[1]+ssm[2]+ssm[3];
    rout[c] = mx; rout[HH+c] = sm/(double)m;
  }
}

// fused epilogue: a3 rows (full overwrite, no memset) | xs rows | perm | mlp
__global__ __launch_bounds__(256) void epilogue_kernel(const float* __restrict__ kp,
    const int* __restrict__ perm3, const int* __restrict__ nbr3,
    const double* __restrict__ r1, const double* __restrict__ r2, const double* __restrict__ r3,
    const float* __restrict__ L1w, const float* __restrict__ L2w, const float* __restrict__ L3w,
    float* out_logp, float* out_xs, float* out_perm, float* out_a3){
  __shared__ double z[256], z1[128], z2[64], z3[40];
  int b = blockIdx.x, t = threadIdx.x;
  if (b < 1024){
    int s0=nbr3[b*KN+0], s1=nbr3[b*KN+1], s2=nbr3[b*KN+2], s3=nbr3[b*KN+3], s4=nbr3[b*KN+4];
    #pragma unroll
    for (int q=0;q<4;q++){
      int col = t + 256*q;
      float v = (col==b||col==s0||col==s1||col==s2||col==s3||col==s4) ? 1.0f : 0.0f;
      out_a3[(size_t)b*1024+col] = v;
    }
  } else if (b < 2048){
    int i = b-1024;
    if (t < HH) out_xs[(size_t)i*HH+t] = kp[(size_t)perm3[i]*HH+t];
  } else if (b == 2048){
    for (int q=t;q<1024;q+=256) out_perm[q] = (float)perm3[q];
  } else {
    z[t] = r1[t]+r2[t]+r3[t];
    __syncthreads();
    if (t<128){ double a=0; for(int k=0;k<256;k++) a += z[k]*(double)L1w[k*128+t]; z1[t]=a>0?a:0; }
    __syncthreads();
    if (t<64){ double a=0; for(int k=0;k<128;k++) a += z1[k]*(double)L2w[k*64+t]; z2[t]=a>0?a:0; }
    __syncthreads();
    if (t<40){ double a=0; for(int k=0;k<64;k++) a += z2[k]*(double)L3w[k*40+t]; z3[t]=a; }
    __syncthreads();
    if (t==0){
      double m=-INFINITY; for(int j=0;j<40;j++) m=fmax(m,z3[j]);
      double s=0; for(int j=0;j<40;j++) s+=exp(z3[j]-m);
      double l=log(s);
      for(int j=0;j<40;j++) out_logp[j] = (float)(z3[j]-m-l);
    }
  }
}

__global__ void enc_kernel(float* out, float v){
  if (threadIdx.x < 40) out[threadIdx.x] = v;
}

extern "C" void kernel_launch(void* const* d_in, const int* in_sizes, int n_in,
                              void* d_out, int out_size, void* d_ws, size_t ws_size,
                              hipStream_t stream){
  const float* kp  = (const float*)d_in[0];
  const float* W1  = (const float*)d_in[2];
  const float* W2  = (const float*)d_in[4];
  const float* W3  = (const float*)d_in[6];
  const float* Wp1 = (const float*)d_in[8];
  const float* Wp2 = (const float*)d_in[10];
  const float* Wp3 = (const float*)d_in[12];
  const float* L1w = (const float*)d_in[14];
  const float* L2w = (const float*)d_in[16];
  const float* L3w = (const float*)d_in[18];

  float* out = (float*)d_out;
  if (out_size != 40 + 128*1024 + 1024 + 1024*1024){
    enc_kernel<<<1,64,0,stream>>>(out, (float)out_size);
    return;
  }

  char* p = (char*)d_ws;
  auto alloc = [&](size_t bytes)->char*{ char* q = p; p += (bytes + 255) & ~(size_t)255; return q; };
  float* G     = (float*)alloc((size_t)N0*HH*4);
  float* h     = (float*)alloc((size_t)N0*HH*4);
  float* hpA   = (float*)alloc((size_t)4096*HH*4);
  float* hpB   = (float*)alloc((size_t)2048*HH*4);
  int* degi    = (int*)alloc(N0*4);
  float* dinvf = (float*)alloc(N0*4);
  int* cnt     = (int*)alloc(N0*4);
  int* slots   = (int*)alloc((size_t)N0*32*4);
  int* nbr0    = (int*)alloc(N0*KN*4);
  int* nbr1    = (int*)alloc(4096*KN*4);
  int* nbr2    = (int*)alloc(2048*KN*4);
  int* nbr3    = (int*)alloc(1024*KN*4);
  int* idx1    = (int*)alloc(4096*4);
  int* idx2    = (int*)alloc(2048*4);
  int* idx3    = (int*)alloc(1024*4);
  int* perm1   = (int*)alloc(4096*4);
  int* perm2   = (int*)alloc(2048*4);
  int* perm3   = (int*)alloc(1024*4);
  int* pos     = (int*)alloc(N0*4);
  float* ybuf  = (float*)alloc(N0*4);
  float* score = (float*)alloc(N0*4);
  unsigned* skey = (unsigned*)alloc(N0*4);
  float* gate  = (float*)alloc(4096*4);
  double* T    = (double*)alloc(HH*8);
  double* TsPart = (double*)alloc(256*8);
  double* r1   = (double*)alloc(256*8);
  double* r2   = (double*)alloc(256*8);
  double* r3   = (double*)alloc(256*8);

  float* out_logp = out;
  float* out_xs   = out + 40;
  float* out_perm = out + 40 + 128*1024;
  float* out_a3   = out_perm + 1024;

  auto run_level = [&](int n, int init, const float* X, const float* W, const float* Wp,
                       int* nbr, int* nbrN, int* idx, int* permPrev, int* permNext,
                       float* hp, double* rout){
    int m = n>>1;
    graph_kernel<<<1,1024,(size_t)n*8,stream>>>(nbr, n, init, degi, dinvf, cnt, slots, T, TsPart);
    gemm32_kernel<<<n/4,128,0,stream>>>(X, W, G, n);
    tpar_kernel<<<64,HH,0,stream>>>(G, dinvf, T, n);
    aggproj_kernel<<<n,HH,0,stream>>>(G, dinvf, degi, cnt, slots, T, Wp, h, ybuf, TsPart, n);
    sagg32_kernel<<<(n+255)/256,256,0,stream>>>(ybuf, dinvf, degi, cnt, slots, TsPart, score, skey, n);
    rank_kernel<<<n/EL,256,0,stream>>>(skey, score, n, idx, gate, pos, permPrev, permNext);
    poolmap_kernel<<<m,HH,0,stream>>>(h, idx, gate, nbr, pos, hp, nbrN, m);
    readout_kernel<<<HH,256,0,stream>>>(hp, rout, m);
  };

  run_level(8192, 1, kp,  W1, Wp1, nbr0, nbr1, idx1, nullptr, perm1, hpA, r1);
  run_level(4096, 0, hpA, W2, Wp2, nbr1, nbr2, idx2, perm1,   perm2, hpB, r2);
  run_level(2048, 0, hpB, W3, Wp3, nbr2, nbr3, idx3, perm2,   perm3, hpA, r3);

  epilogue_kernel<<<2050,256,0,stream>>>(kp, perm3, nbr3, r1, r2, r3,
                                         L1w, L2w, L3w,
                                         out_logp, out_xs, out_perm, out_a3);
}